// Round 8
// baseline (356.501 us; speedup 1.0000x reference)
//
#include <hip/hip_runtime.h>
#include <hip/hip_bf16.h>

typedef __attribute__((ext_vector_type(8))) short bf16x8;
typedef __attribute__((ext_vector_type(4))) float f32x4;

#define N_OUT 65536
#define CIN   256
#define COUT  512
#define BM    128
#define BNB   128   // block N-width
#define BK    32
#define NKS   64    // 2048 / 32 K-steps

__device__ __forceinline__ unsigned short f2bf(float f) {
  union { __hip_bfloat16 h; unsigned short u; } c;
  c.h = __float2bfloat16(f);
  return c.u;
}

__device__ __forceinline__ bf16x8 pack8(f32x4 a, f32x4 b) {
  unsigned short u[8];
  u[0] = f2bf(a.x); u[1] = f2bf(a.y); u[2] = f2bf(a.z); u[3] = f2bf(a.w);
  u[4] = f2bf(b.x); u[5] = f2bf(b.y); u[6] = f2bf(b.z); u[7] = f2bf(b.w);
  return *reinterpret_cast<bf16x8*>(u);
}

__device__ __forceinline__ void gload_lds16f(const float* g, float* l) {
  __builtin_amdgcn_global_load_lds(
      (const __attribute__((address_space(1))) void*)g,
      (__attribute__((address_space(3))) void*)l, 16, 0, 0);
}
__device__ __forceinline__ void gload_lds16u(const unsigned short* g, unsigned short* l) {
  __builtin_amdgcn_global_load_lds(
      (const __attribute__((address_space(1))) void*)g,
      (__attribute__((address_space(3))) void*)l, 16, 0, 0);
}

// --- weight prep: W[k][n] f32 -> Wt bf16 tiled [kb][slot][n][w]:
//     Wt[kb*16384 + s*4096 + n*8 + w] = bf16(W[(kb*32 + s*8 + w)*512 + n])
__global__ void wprep_kernel(const float* __restrict__ W, unsigned short* __restrict__ Wt) {
  int idx = blockIdx.x * blockDim.x + threadIdx.x;
  if (idx >= 64 * 4 * COUT) return;
  int n  = idx & (COUT - 1);
  int s  = (idx >> 9) & 3;
  int kb = idx >> 11;
  unsigned short tmp[8];
#pragma unroll
  for (int w = 0; w < 8; ++w)
    tmp[w] = f2bf(W[(size_t)(kb * 32 + s * 8 + w) * COUT + n]);
  *reinterpret_cast<bf16x8*>(Wt + ((size_t)kb * 16384 + s * 4096 + n * 8)) =
      *reinterpret_cast<bf16x8*>(tmp);
}

// --- main GEMM: 128x128 blocks, 8 waves, wave tile 32x64, 3-buffer rings,
//     phase-split K-step (T3/T4/T5): early DMA issue, counted vmcnt(3),
//     two {barrier; lgkm0; MFMA-cluster} phases per step. 2 blocks/CU.
__global__ __launch_bounds__(512, 4) void gemm_kernel(
    const float* __restrict__ data,
    const int*   __restrict__ neigh,
    const unsigned short* __restrict__ Wt,
    float* __restrict__ out,
    float* __restrict__ psum,
    float* __restrict__ psq)
{
  __shared__ union {
    struct {
      float          a[3][BM * BK];    // 3 x 16 KB, 16B chunks XOR-swizzled
      unsigned short b[3][BK * BNB];   // 3 x 8 KB, [slot][128 n][8 k]
    } r;                               // 72 KB
    struct { float S[4][BNB]; float Q[4][BNB]; } st;   // 4 KB overlay
  } sm;
  __shared__ unsigned int offs[BM * 8];   // 4 KB

  const int tid = threadIdx.x;
  const int l   = tid & 63;
  const int w   = tid >> 6;       // 8 waves
  const int wr  = w >> 1;         // 0..3 (32-row strip)
  const int wc  = w & 1;          // 0..1 (64-col strip)
  const int lg  = l >> 4;
  const int lm  = l & 15;

  // XCD quad-pairing (2048 blocks, HW round-robins bid%8 across XCDs):
  // the 4 n-quarters of one m-panel are adjacent on one XCD -> A L2-shared.
  const int bid = blockIdx.x;
  const int xcd = bid & 7;
  const int jj  = bid >> 3;               // 0..255 within XCD
  const int mb  = xcd * 64 + (jj >> 2);   // 0..511
  const int nq  = jj & 3;
  const int n0  = nq * BNB;
  const int m0  = mb * BM;
  const int pidx = mb * 4 + nq;

  // neigh -> LDS offset table (float offsets into data)
  for (int e = tid; e < BM * 8; e += 512)
    offs[e] = ((unsigned)neigh[(size_t)m0 * 8 + e]) << 8;
  __syncthreads();

  f32x4 acc[2][4];
#pragma unroll
  for (int i = 0; i < 2; ++i)
#pragma unroll
    for (int j2 = 0; j2 < 4; ++j2) acc[i][j2] = (f32x4){0.f, 0.f, 0.f, 0.f};

  const int lrow = l >> 3;
  const int ra   = (w * 16 + lrow) * 8;
  const int rb   = (w * 16 + 8 + lrow) * 8;
  const int swzf = ((l & 7) ^ lrow) << 2;
  const unsigned short* bsrc0 = Wt + (w >> 1) * 4096 + n0 * 8 + (w & 1) * 512 + l * 8;
  unsigned short* bdst_base;   // per-buf computed in macro

  // A: 2 DMA/wave/step (rule-21 pre-swizzled source, linear LDS dest)
#define AISSUE(t_, buf_) do { \
    int cn_ = (t_) >> 3; \
    int k0_ = ((t_) & 7) * BK; \
    unsigned o0_ = offs[ra + cn_]; \
    unsigned o1_ = offs[rb + cn_]; \
    gload_lds16f(data + o0_ + k0_ + swzf, &sm.r.a[buf_][(w * 16) * BK]); \
    gload_lds16f(data + o1_ + k0_ + swzf, &sm.r.a[buf_][(w * 16 + 8) * BK]); \
  } while (0)

  // B: 1 DMA/wave/step (wave w: slot w>>1, half w&1; 1KB linear)
#define BISSUE(t_, buf_) do { \
    gload_lds16u(bsrc0 + (size_t)(t_) * 16384, \
                 &sm.r.b[buf_][(w >> 1) * 1024 + (w & 1) * 512]); \
  } while (0)

#define MFMA2(g_, bf0_, bf1_) do { \
    acc[0][2*(g_)]   = __builtin_amdgcn_mfma_f32_16x16x32_bf16(af0, bf0_, acc[0][2*(g_)],   0, 0, 0); \
    acc[1][2*(g_)]   = __builtin_amdgcn_mfma_f32_16x16x32_bf16(af1, bf0_, acc[1][2*(g_)],   0, 0, 0); \
    acc[0][2*(g_)+1] = __builtin_amdgcn_mfma_f32_16x16x32_bf16(af0, bf1_, acc[0][2*(g_)+1], 0, 0, 0); \
    acc[1][2*(g_)+1] = __builtin_amdgcn_mfma_f32_16x16x32_bf16(af1, bf1_, acc[1][2*(g_)+1], 0, 0, 0); \
  } while (0)

  // ---- prologue: steps 0,1 in flight (3 ops/wave each)
  AISSUE(0, 0); BISSUE(0, 0);
  AISSUE(1, 1); BISSUE(1, 1);

  const int R0 = wr * 32 + lm;        // af0 row
  const int R1 = wr * 32 + 16 + lm;   // af1 row

#pragma unroll 1
  for (int t = 0; t < NKS; ++t) {
    // entry: retire step t's 3 ops (keep t+1's 3 in flight); never full drain
    if (t < NKS - 1) asm volatile("s_waitcnt vmcnt(3)" ::: "memory");
    else             asm volatile("s_waitcnt vmcnt(0)" ::: "memory");
    __builtin_amdgcn_s_barrier();
    asm volatile("" ::: "memory");

    const int cur = t % 3;
    const int pre = (t + 2) % 3;

    // ---- ph0: issue ds_reads (A-frags + B group 0) and next-tile DMA
    const f32x4* ap0 = reinterpret_cast<const f32x4*>(&sm.r.a[cur][R0 * BK]);
    const f32x4* ap1 = reinterpret_cast<const f32x4*>(&sm.r.a[cur][R1 * BK]);
    f32x4 x00 = ap0[(2 * lg)     ^ (R0 & 7)];
    f32x4 x01 = ap0[(2 * lg + 1) ^ (R0 & 7)];
    f32x4 x10 = ap1[(2 * lg)     ^ (R1 & 7)];
    f32x4 x11 = ap1[(2 * lg + 1) ^ (R1 & 7)];
    bf16x8 b0 = *reinterpret_cast<const bf16x8*>(
        &sm.r.b[cur][lg * 1024 + (wc * 64 + 0 * 16 + lm) * 8]);
    bf16x8 b1 = *reinterpret_cast<const bf16x8*>(
        &sm.r.b[cur][lg * 1024 + (wc * 64 + 1 * 16 + lm) * 8]);
    if (t + 2 < NKS) { AISSUE(t + 2, pre); BISSUE(t + 2, pre); }
    __builtin_amdgcn_s_barrier();
    asm volatile("s_waitcnt lgkmcnt(0)" ::: "memory");
    __builtin_amdgcn_sched_barrier(0);
    bf16x8 af0 = pack8(x00, x01);
    bf16x8 af1 = pack8(x10, x11);
    __builtin_amdgcn_s_setprio(1);
    MFMA2(0, b0, b1);
    __builtin_amdgcn_s_setprio(0);

    // ---- ph1: B group 1 reads overlap other waves' ph0 MFMA cluster
    bf16x8 b2 = *reinterpret_cast<const bf16x8*>(
        &sm.r.b[cur][lg * 1024 + (wc * 64 + 2 * 16 + lm) * 8]);
    bf16x8 b3 = *reinterpret_cast<const bf16x8*>(
        &sm.r.b[cur][lg * 1024 + (wc * 64 + 3 * 16 + lm) * 8]);
    __builtin_amdgcn_s_barrier();
    asm volatile("s_waitcnt lgkmcnt(0)" ::: "memory");
    __builtin_amdgcn_sched_barrier(0);
    __builtin_amdgcn_s_setprio(1);
    MFMA2(1, b2, b3);
    __builtin_amdgcn_s_setprio(0);
    asm volatile("" ::: "memory");
  }

  // ---- epilogue 1: raw out (C layout: col = lane&15, row = (lane>>4)*4 + reg)
#pragma unroll
  for (int mi = 0; mi < 2; ++mi) {
#pragma unroll
    for (int r = 0; r < 4; ++r) {
      size_t row = (size_t)(m0 + wr * 32 + mi * 16 + lg * 4 + r);
      float* op = out + row * COUT + n0 + wc * 64 + lm;
#pragma unroll
      for (int ni = 0; ni < 4; ++ni) op[ni * 16] = acc[mi][ni][r];
    }
  }

  // ---- epilogue 2: deterministic per-block column sums/sumsq
  __syncthreads();   // all DMA retired (vmcnt(0)) + all LDS reads done
#pragma unroll
  for (int ni = 0; ni < 4; ++ni) {
    float s1 = 0.f, s2 = 0.f;
#pragma unroll
    for (int mi = 0; mi < 2; ++mi)
#pragma unroll
      for (int r = 0; r < 4; ++r) { float v = acc[mi][ni][r]; s1 += v; s2 += v * v; }
    s1 += __shfl_xor(s1, 16, 64); s1 += __shfl_xor(s1, 32, 64);
    s2 += __shfl_xor(s2, 16, 64); s2 += __shfl_xor(s2, 32, 64);
    if (l < 16) {
      sm.st.S[wr][wc * 64 + ni * 16 + l] = s1;
      sm.st.Q[wr][wc * 64 + ni * 16 + l] = s2;
    }
  }
  __syncthreads();
  if (tid < BNB) {
    float S = sm.st.S[0][tid] + sm.st.S[1][tid] + sm.st.S[2][tid] + sm.st.S[3][tid];
    psum[(size_t)pidx * BNB + tid] = S;
  } else if (tid < 2 * BNB) {
    int c = tid - BNB;
    float Q = sm.st.Q[0][c] + sm.st.Q[1][c] + sm.st.Q[2][c] + sm.st.Q[3][c];
    psq[(size_t)pidx * BNB + c] = Q;
  }
#undef AISSUE
#undef BISSUE
#undef MFMA2
}

// --- stats reduction, stage 1: partials [512 mb][4 nq][128] -> 64 per column
__global__ void reduce1_kernel(const float* __restrict__ psum, const float* __restrict__ psq,
                               float* __restrict__ p2) {
  int c = threadIdx.x, b = blockIdx.x;
  int nq = c >> 7, crel = c & 127;
  float s = 0.f, q = 0.f;
#pragma unroll
  for (int j2 = 0; j2 < 8; ++j2) {
    size_t pi = (size_t)((b * 8 + j2) * 4 + nq);
    s += psum[pi * 128 + crel];
    q += psq [pi * 128 + crel];
  }
  p2[b * 1024 + c] = s;
  p2[b * 1024 + 512 + c] = q;
}

// --- stats reduction, stage 2: mean/var -> per-column scale/shift
__global__ void reduce2_kernel(const float* __restrict__ p2,
                               const float* __restrict__ gamma,
                               const float* __restrict__ beta,
                               float* __restrict__ scsh) {
  int c = threadIdx.x;
  float s = 0.f, q = 0.f;
  for (int b = 0; b < 64; ++b) { s += p2[b * 1024 + c]; q += p2[b * 1024 + 512 + c]; }
  float mean = s * (1.f / 65536.f);
  float var  = q * (1.f / 65536.f) - mean * mean;
  float rs   = rsqrtf(var + 1e-5f);
  float sc   = gamma[c] * rs;
  scsh[c] = sc;
  scsh[COUT + c] = beta[c] - mean * sc;   // conv bias cancels in BN
}

// --- apply BN in-place
__global__ void bn_kernel(float* __restrict__ out, const float* __restrict__ scsh) {
  __shared__ float sc[COUT], sh[COUT];
  int t = threadIdx.x;
  sc[t] = scsh[t];
  sh[t] = scsh[COUT + t];
  __syncthreads();
  f32x4* o4 = reinterpret_cast<f32x4*>(out);
  const size_t total  = (size_t)N_OUT * COUT / 4;
  const size_t stride = (size_t)gridDim.x * blockDim.x;
  for (size_t i = (size_t)blockIdx.x * blockDim.x + t; i < total; i += stride) {
    f32x4 v = o4[i];
    int c = ((int)(i & 127)) * 4;
    v.x = v.x * sc[c]     + sh[c];
    v.y = v.y * sc[c + 1] + sh[c + 1];
    v.z = v.z * sc[c + 2] + sh[c + 2];
    v.w = v.w * sc[c + 3] + sh[c + 3];
    o4[i] = v;
  }
}

extern "C" void kernel_launch(void* const* d_in, const int* in_sizes, int n_in,
                              void* d_out, int out_size, void* d_ws, size_t ws_size,
                              hipStream_t stream) {
  const float* data   = (const float*)d_in[0];
  const float* weight = (const float*)d_in[1];
  const float* gamma  = (const float*)d_in[3];
  const float* beta   = (const float*)d_in[4];
  const int*   neigh  = (const int*)d_in[5];
  float* out = (float*)d_out;

  char* ws = (char*)d_ws;
  unsigned short* Wt = (unsigned short*)ws;                        // 2 MB
  float* psum = (float*)(ws + (2u << 20));                         // 1 MB
  float* psq  = (float*)(ws + (3u << 20));                         // 1 MB
  float* p2   = (float*)(ws + (4u << 20));                         // 256 KB
  float* scsh = (float*)(ws + (4u << 20) + (256u << 10));          // 4 KB

  wprep_kernel<<<512, 256, 0, stream>>>(weight, Wt);
  gemm_kernel<<<2048, 512, 0, stream>>>(data, neigh, Wt, out, psum, psq);
  reduce1_kernel<<<64, 512, 0, stream>>>(psum, psq, p2);
  reduce2_kernel<<<1, 512, 0, stream>>>(p2, gamma, beta, scsh);
  bn_kernel<<<2048, 512, 0, stream>>>(out, scsh);
}

// Round 9
// 330.172 us; speedup vs baseline: 1.0797x; 1.0797x over previous
//
#include <hip/hip_runtime.h>
#include <hip/hip_bf16.h>

typedef __attribute__((ext_vector_type(8))) short bf16x8;
typedef __attribute__((ext_vector_type(4))) float f32x4;

#define N_OUT 65536
#define CIN   256
#define COUT  512
#define BM    128
#define BN    256
#define BK    32
#define NKS   64    // 2048 / 32 K-steps
#define ALD   40    // A LDS row stride in shorts (32 data + 8 pad = 80B, b128-aligned)

__device__ __forceinline__ unsigned short f2bf(float f) {
  union { __hip_bfloat16 h; unsigned short u; } c;
  c.h = __float2bfloat16(f);
  return c.u;
}

__device__ __forceinline__ bf16x8 pack8(f32x4 a, f32x4 b) {
  unsigned short u[8];
  u[0] = f2bf(a.x); u[1] = f2bf(a.y); u[2] = f2bf(a.z); u[3] = f2bf(a.w);
  u[4] = f2bf(b.x); u[5] = f2bf(b.y); u[6] = f2bf(b.z); u[7] = f2bf(b.w);
  return *reinterpret_cast<bf16x8*>(u);
}

__device__ __forceinline__ void gload_lds16u(const unsigned short* g, unsigned short* l) {
  __builtin_amdgcn_global_load_lds(
      (const __attribute__((address_space(1))) void*)g,
      (__attribute__((address_space(3))) void*)l, 16, 0, 0);
}

// --- weight prep: W[k][n] f32 -> Wt bf16 tiled [kb][slot][n][w]:
//     Wt[kb*16384 + s*4096 + n*8 + w] = bf16(W[(kb*32 + s*8 + w)*512 + n])
__global__ void wprep_kernel(const float* __restrict__ W, unsigned short* __restrict__ Wt) {
  int idx = blockIdx.x * blockDim.x + threadIdx.x;
  if (idx >= 64 * 4 * COUT) return;
  int n  = idx & (COUT - 1);
  int s  = (idx >> 9) & 3;
  int kb = idx >> 11;
  unsigned short tmp[8];
#pragma unroll
  for (int w = 0; w < 8; ++w)
    tmp[w] = f2bf(W[(size_t)(kb * 32 + s * 8 + w) * COUT + n]);
  *reinterpret_cast<bf16x8*>(Wt + ((size_t)kb * 16384 + s * 4096 + n * 8)) =
      *reinterpret_cast<bf16x8*>(tmp);
}

// --- main GEMM: 128x256 blocks, 8 waves, wave tile 64x64 (acc=64 regs),
//     A reg-staged->bf16 LDS (T14 async split, padded conflict-free layout),
//     B via global_load_lds, one vmcnt(0)/iter on phase-old ops, 2 blk/CU.
__global__ __launch_bounds__(512, 4) void gemm_kernel(
    const float* __restrict__ data,
    const int*   __restrict__ neigh,
    const unsigned short* __restrict__ Wt,
    float* __restrict__ out,
    float* __restrict__ psum,
    float* __restrict__ psq)
{
  __shared__ union {
    struct {
      unsigned short a[2][BM * ALD];   // 2 x 10 KB bf16, padded rows
      unsigned short b[2][BK * BN];    // 2 x 16 KB bf16, linear
    } r;                               // 52 KB
    struct { float S[2][BN]; float Q[2][BN]; } st;   // 4 KB overlay
  } sm;
  __shared__ unsigned int offs[BM * 8];   // 4 KB

  const int tid = threadIdx.x;
  const int l   = tid & 63;
  const int w   = tid >> 6;       // 8 waves
  const int wr  = w >> 2;         // 0..1 (64-row strip)
  const int wc  = w & 3;          // 0..3 (64-col strip)
  const int lg  = l >> 4;
  const int lm  = l & 15;

  // XCD-pairing map (1024 blocks; HW round-robins bid%8 across 8 XCDs):
  // the two n-halves of one m-panel are adjacent on one XCD -> A L2-shared.
  const int bid = blockIdx.x;
  const int xcd = bid & 7;
  const int j   = bid >> 3;
  const int mb  = xcd * 64 + (j >> 1);
  const int nh  = j & 1;
  const int n0  = nh * BN;
  const int m0  = mb * BM;
  const int pidx = mb * 2 + nh;

  // neigh -> LDS offset table
  for (int e = tid; e < BM * 8; e += 512)
    offs[e] = ((unsigned)neigh[(size_t)m0 * 8 + e]) << 8;
  __syncthreads();

  f32x4 acc[4][4];
#pragma unroll
  for (int i = 0; i < 4; ++i)
#pragma unroll
    for (int jj = 0; jj < 4; ++jj) acc[i][jj] = (f32x4){0.f, 0.f, 0.f, 0.f};

  // A staging assignment: thread -> (row = tid>>2, 8-float chunk = tid&3)
  const int arow  = tid >> 2;
  const int achk  = tid & 3;
  const int arow8 = arow * 8;
  f32x4 sa0, sa1;                 // in-flight A (one step, 8 floats)

  const int q0 = w * 2;           // B chunk pair for this wave
  const unsigned short* bbase =
      Wt + n0 * 8 + (q0 >> 2) * 4096 + (q0 & 3) * 512 + l * 8;

  // A global load -> regs (issued a full compute-phase before use)
#define AG(t_) do { \
    int cn_ = (t_) >> 3; \
    int k0_ = ((t_) & 7) * BK; \
    const f32x4* p_ = reinterpret_cast<const f32x4*>(data + offs[arow8 + cn_] + k0_ + achk * 8); \
    sa0 = p_[0]; sa1 = p_[1]; \
  } while (0)

  // A convert + LDS write (after vmcnt(0) retires the AG)
#define AW(buf_) do { \
    *reinterpret_cast<bf16x8*>(&sm.r.a[buf_][arow * ALD + achk * 8]) = pack8(sa0, sa1); \
  } while (0)

  // B: 2 DMA/wave/step, linear 512-short chunks
#define BD(t_, buf_) do { \
    const unsigned short* bs_ = bbase + (size_t)(t_) * 16384; \
    gload_lds16u(bs_,       &sm.r.b[buf_][q0 * 512]); \
    gload_lds16u(bs_ + 512, &sm.r.b[buf_][q0 * 512 + 512]); \
  } while (0)

#define COMPUTE(buf_) do { \
    bf16x8 af_[4]; \
    _Pragma("unroll") \
    for (int mi_ = 0; mi_ < 4; ++mi_) { \
      int R_ = wr * 64 + mi_ * 16 + lm; \
      af_[mi_] = *reinterpret_cast<const bf16x8*>(&sm.r.a[buf_][R_ * ALD + lg * 8]); \
    } \
    _Pragma("unroll") \
    for (int ni_ = 0; ni_ < 4; ++ni_) { \
      bf16x8 bfr_ = *reinterpret_cast<const bf16x8*>( \
          &sm.r.b[buf_][lg * 2048 + (wc * 64 + ni_ * 16 + lm) * 8]); \
      _Pragma("unroll") \
      for (int mi_ = 0; mi_ < 4; ++mi_) \
        acc[mi_][ni_] = __builtin_amdgcn_mfma_f32_16x16x32_bf16(af_[mi_], bfr_, acc[mi_][ni_], 0, 0, 0); \
    } \
  } while (0)

  // ---- prologue: steps 0,1 staged; step-2 A loads in flight
  AG(0);
  asm volatile("s_waitcnt vmcnt(0)" ::: "memory");
  AW(0); BD(0, 0);
  AG(1);
  asm volatile("s_waitcnt vmcnt(0)" ::: "memory");   // drains B(0) too (needed first)
  AW(1); BD(1, 1);
  AG(2);

#pragma unroll 1
  for (int t = 0; t < NKS; ++t) {
    asm volatile("s_waitcnt lgkmcnt(0)" ::: "memory");   // own ds_writes done
    __builtin_amdgcn_s_barrier();
    asm volatile("" ::: "memory");
    COMPUTE(t & 1);
    asm volatile("" ::: "memory");
    __builtin_amdgcn_s_barrier();        // WAR: all reads done before overwrite
    if (t + 2 < NKS) {
      // A(t+2) regs are a full compute old; B(t+1) a full iter old -> ~no stall
      asm volatile("s_waitcnt vmcnt(0)" ::: "memory");
      AW(t & 1);                         // bf16 A(t+2) into freed buffer
      BD(t + 2, t & 1);
      if (t + 3 < NKS) AG(t + 3);
    } else if (t == NKS - 2) {
      asm volatile("s_waitcnt vmcnt(0)" ::: "memory");   // drain B(NKS-1)
    }
  }

  // ---- epilogue 1: raw out (C layout: col = lane&15, row = (lane>>4)*4 + reg)
#pragma unroll
  for (int mi = 0; mi < 4; ++mi) {
#pragma unroll
    for (int r = 0; r < 4; ++r) {
      size_t row = (size_t)(m0 + wr * 64 + mi * 16 + lg * 4 + r);
      float* op = out + row * COUT + n0 + wc * 64 + lm;
#pragma unroll
      for (int ni = 0; ni < 4; ++ni) op[ni * 16] = acc[mi][ni][r];
    }
  }

  // ---- epilogue 2: deterministic per-block column sums/sumsq
  __syncthreads();   // all DMA retired + LDS reads done before overlay
#pragma unroll
  for (int ni = 0; ni < 4; ++ni) {
    float s1 = 0.f, s2 = 0.f;
#pragma unroll
    for (int mi = 0; mi < 4; ++mi)
#pragma unroll
      for (int r = 0; r < 4; ++r) { float v = acc[mi][ni][r]; s1 += v; s2 += v * v; }
    s1 += __shfl_xor(s1, 16, 64); s1 += __shfl_xor(s1, 32, 64);
    s2 += __shfl_xor(s2, 16, 64); s2 += __shfl_xor(s2, 32, 64);
    if (l < 16) {
      sm.st.S[wr][wc * 64 + ni * 16 + l] = s1;
      sm.st.Q[wr][wc * 64 + ni * 16 + l] = s2;
    }
  }
  __syncthreads();
  if (tid < BN) {
    psum[(size_t)pidx * BN + tid] = sm.st.S[0][tid] + sm.st.S[1][tid];
  } else {
    int c = tid - BN;
    psq[(size_t)pidx * BN + c] = sm.st.Q[0][c] + sm.st.Q[1][c];
  }
#undef AG
#undef AW
#undef BD
#undef COMPUTE
}

// --- stats reduction, stage 1: partials [512 mb][2 nh][256] -> 64 per column
__global__ void reduce1_kernel(const float* __restrict__ psum, const float* __restrict__ psq,
                               float* __restrict__ p2) {
  int c = threadIdx.x, b = blockIdx.x;
  int h = c >> 8, crel = c & 255;
  float s = 0.f, q = 0.f;
#pragma unroll
  for (int jj = 0; jj < 8; ++jj) {
    size_t pi = (size_t)((b * 8 + jj) * 2 + h);
    s += psum[pi * 256 + crel];
    q += psq [pi * 256 + crel];
  }
  p2[b * 1024 + c] = s;
  p2[b * 1024 + 512 + c] = q;
}

// --- stats reduction, stage 2: mean/var -> per-column scale/shift
__global__ void reduce2_kernel(const float* __restrict__ p2,
                               const float* __restrict__ gamma,
                               const float* __restrict__ beta,
                               float* __restrict__ scsh) {
  int c = threadIdx.x;
  float s = 0.f, q = 0.f;
  for (int b = 0; b < 64; ++b) { s += p2[b * 1024 + c]; q += p2[b * 1024 + 512 + c]; }
  float mean = s * (1.f / 65536.f);
  float var  = q * (1.f / 65536.f) - mean * mean;
  float rs   = rsqrtf(var + 1e-5f);
  float sc   = gamma[c] * rs;
  scsh[c] = sc;
  scsh[COUT + c] = beta[c] - mean * sc;   // conv bias cancels in BN
}

// --- apply BN in-place
__global__ void bn_kernel(float* __restrict__ out, const float* __restrict__ scsh) {
  __shared__ float sc[COUT], sh[COUT];
  int t = threadIdx.x;
  sc[t] = scsh[t];
  sh[t] = scsh[COUT + t];
  __syncthreads();
  f32x4* o4 = reinterpret_cast<f32x4*>(out);
  const size_t total  = (size_t)N_OUT * COUT / 4;
  const size_t stride = (size_t)gridDim.x * blockDim.x;
  for (size_t i = (size_t)blockIdx.x * blockDim.x + t; i < total; i += stride) {
    f32x4 v = o4[i];
    int c = ((int)(i & 127)) * 4;
    v.x = v.x * sc[c]     + sh[c];
    v.y = v.y * sc[c + 1] + sh[c + 1];
    v.z = v.z * sc[c + 2] + sh[c + 2];
    v.w = v.w * sc[c + 3] + sh[c + 3];
    o4[i] = v;
  }
}

extern "C" void kernel_launch(void* const* d_in, const int* in_sizes, int n_in,
                              void* d_out, int out_size, void* d_ws, size_t ws_size,
                              hipStream_t stream) {
  const float* data   = (const float*)d_in[0];
  const float* weight = (const float*)d_in[1];
  const float* gamma  = (const float*)d_in[3];
  const float* beta   = (const float*)d_in[4];
  const int*   neigh  = (const int*)d_in[5];
  float* out = (float*)d_out;

  char* ws = (char*)d_ws;
  unsigned short* Wt = (unsigned short*)ws;                        // 2 MB
  float* psum = (float*)(ws + (2u << 20));                         // 1 MB
  float* psq  = (float*)(ws + (3u << 20));                         // 1 MB
  float* p2   = (float*)(ws + (4u << 20));                         // 256 KB
  float* scsh = (float*)(ws + (4u << 20) + (256u << 10));          // 4 KB

  wprep_kernel<<<512, 256, 0, stream>>>(weight, Wt);
  gemm_kernel<<<1024, 512, 0, stream>>>(data, neigh, Wt, out, psum, psq);
  reduce1_kernel<<<64, 512, 0, stream>>>(psum, psq, p2);
  reduce2_kernel<<<1, 512, 0, stream>>>(p2, gamma, beta, scsh);
  bn_kernel<<<2048, 512, 0, stream>>>(out, scsh);
}